// Round 17
// baseline (11600.936 us; speedup 1.0000x reference)
//
#include <hip/hip_runtime.h>
#include <hip/hip_bf16.h>

#define T_STEPS 1024
#define NWG     64

typedef __attribute__((ext_vector_type(8))) short          bf16x8;
typedef __attribute__((ext_vector_type(4))) float          f32x4;
typedef __attribute__((ext_vector_type(8))) unsigned short u16x8;
typedef unsigned long long ull;

static __device__ __forceinline__ unsigned short f2bf_bits(float f) {
    union { __hip_bfloat16 h; unsigned short u; } cv;
    cv.h = __float2bfloat16(f);
    return cv.u;
}

// ---------------------------------------------------------------------------
// P1: fold ln_g into weights, cast bf16, emit in MFMA B-fragment order.
// Chunk layout: [g][part][tn][kstep][lane][e]
//   k  = part*512 + kstep*32 + (lane>>4)*8 + e
//   c  = tn*16 + (lane&15);  n = (c>>3)*512 + g*8 + (c&7)
// ---------------------------------------------------------------------------
__global__ __launch_bounds__(256) void pack_weights(
    const float* __restrict__ Wf, const float* __restrict__ Wi,
    const float* __restrict__ Wg, const float* __restrict__ Wo,
    const float* __restrict__ ln_g, __hip_bfloat16* __restrict__ pack)
{
    __shared__ unsigned short tile[512 * 32];   // [k_local][c]
    const int blk = blockIdx.x;
    const int g = blk >> 1, part = blk & 1;
    const int tid = threadIdx.x;

    for (int idx = tid; idx < 512 * 32; idx += 256) {
        int kl = idx >> 5, c = idx & 31;
        int q = c >> 3, jl = c & 7;
        int k = part * 512 + kl;
        const float* W = (q == 0) ? Wf : ((q == 1) ? Wi : ((q == 2) ? Wg : Wo));
        float v = W[k * 512 + g * 8 + jl] * ln_g[k];
        tile[kl * 32 + c] = f2bf_bits(v);
    }
    __syncthreads();

    unsigned short* out = (unsigned short*)(pack + (size_t)blk * 16384);
    for (int s = tid; s < 2048; s += 256) {        // slot = tn*1024 + ks*64 + l
        int tn = s >> 10, ks = (s >> 6) & 15, l = s & 63;
        u16x8 v;
#pragma unroll
        for (int e = 0; e < 8; ++e) {
            int klocal = ks * 32 + ((l >> 4) * 8) + e;
            int c = tn * 16 + (l & 15);
            v[e] = tile[klocal * 32 + c];
        }
        *(u16x8*)(out + (size_t)s * 8) = v;
    }
}

// ---------------------------------------------------------------------------
// P2: S[n] = sum_k ln_g[k]*W[k,n],  C[n] = sum_k ln_b[k]*W[k,n] + bias[n]
// ---------------------------------------------------------------------------
__global__ __launch_bounds__(256) void compute_sc(
    const float* __restrict__ Wf, const float* __restrict__ Wi,
    const float* __restrict__ Wg, const float* __restrict__ Wo,
    const float* __restrict__ bf_, const float* __restrict__ bi_,
    const float* __restrict__ bg_, const float* __restrict__ bo_,
    const float* __restrict__ ln_g, const float* __restrict__ ln_b,
    float* __restrict__ S, float* __restrict__ C)
{
    int n = blockIdx.x * 256 + threadIdx.x;        // 0..2047
    int q = n >> 9, j = n & 511;
    const float* W = (q == 0) ? Wf : ((q == 1) ? Wi : ((q == 2) ? Wg : Wo));
    const float* bb = (q == 0) ? bf_ : ((q == 1) ? bi_ : ((q == 2) ? bg_ : bo_));
    float accS = 0.f, accC = 0.f;
    for (int k = 0; k < 1024; ++k) {
        float w = W[k * 512 + j];
        accS += ln_g[k] * w;
        accC += ln_b[k] * w;
    }
    S[n] = accS;
    C[n] = accC + bb[j];
}

// ---------------------------------------------------------------------------
// P3: x -> bf16 copy + per-row sum / sumsq (fp32). One wave per (t,b) row.
// ---------------------------------------------------------------------------
__global__ __launch_bounds__(256) void prep_x(
    const float* __restrict__ x, __hip_bfloat16* __restrict__ xb,
    float* __restrict__ sx, float* __restrict__ sq)
{
    const int wave = threadIdx.x >> 6, lane = threadIdx.x & 63;
    const long row = (long)blockIdx.x * 4 + wave;  // 0..65535
    const float* src = x + row * 512 + lane * 8;
    float4 a = *(const float4*)src;
    float4 b = *(const float4*)(src + 4);
    float vals[8] = {a.x, a.y, a.z, a.w, b.x, b.y, b.z, b.w};
    u16x8 o;
    float s = 0.f, qq = 0.f;
#pragma unroll
    for (int e = 0; e < 8; ++e) {
        s += vals[e];
        qq += vals[e] * vals[e];
        o[e] = f2bf_bits(vals[e]);
    }
    *(u16x8*)((unsigned short*)xb + row * 512 + lane * 8) = o;
#pragma unroll
    for (int d = 1; d < 64; d <<= 1) {
        s  += __shfl_xor(s, d);
        qq += __shfl_xor(qq, d);
    }
    if (lane == 0) { sx[row] = s; sq[row] = qq; }
}

// ---------------------------------------------------------------------------
// Main persistent kernel: 64 WGs x 512 threads — R16 structure with the sync
// replaced by SELF-VALIDATING TAGGED h WORDS:
//   hxt[parity][wg][row 64][col 8] u32, word = (bf16 << 16) | step_tag.
//   Producer: ONE relaxed agent 4B store per thread. No drain, no flag.
//   Consumer: retry-load its 32 tagged words until all tags == t (s_sleep
//   backoff). Tag==t <=> word holds h_t (parity t&1; buffer zeroed => tag 0
//   == h_0). Upper 16 bits ARE the f32 bit pattern (exact stats, free).
// Wave w: m = w>>1 (16-row M tile), kh = w&1 (K half); wave checks only its
// own kh-half regions (32 of 64). Barrier A is the only per-step barrier
// (zHs/rs parity-buffered, R16). Skew safety: overwriting h_t requires all
// WGs past step-t barrier A => all h_t reads complete.
// Thread t: b = t>>3, jl = t&7 owns gate/state element (b, 8g+jl).
// ---------------------------------------------------------------------------
__global__ __launch_bounds__(512, 2) void qlstm_main(
    const float* __restrict__ x,
    const __hip_bfloat16* __restrict__ pack,
    const float* __restrict__ Sarr, const float* __restrict__ Carr,
    const __hip_bfloat16* __restrict__ xb,
    const float* __restrict__ sx, const float* __restrict__ sq,
    unsigned int* __restrict__ hxt,     // [2][64 wg][64 row][8] u32 (zeroed)
    float* __restrict__ out)            // stacked | hx | cx (fp32)
{
    const int g = blockIdx.x;
    const int tid = threadIdx.x;
    const int wave = tid >> 6, lane = tid & 63;
    const int m = wave >> 1, kh = wave & 1;
    const int b = tid >> 3, jl = tid & 7, jg = g * 8 + jl;

    __shared__ float zXs[2][2][2112];          // [parity][kh][row*33+col]
    __shared__ float zHs[2][2][2112];          // [parity][kh]
    __shared__ float rsS[2][64][2], rsQ[2][64][2];
    __shared__ float Scol[32], Ccol[32];

    if (tid < 32) {
        int n = (tid >> 3) * 512 + g * 8 + (tid & 7);
        Scol[tid] = Sarr[n];
        Ccol[tid] = Carr[n];
    }

    // Persistent B-fragments: 4 x 8 frags x 4 VGPR = 128 regs.
    bf16x8 Bx0[8], Bx1[8], Bh0[8], Bh1[8];
    {
        const bf16x8* px = (const bf16x8*)(pack + (size_t)(g * 2 + 0) * 16384);
        const bf16x8* ph = (const bf16x8*)(pack + (size_t)(g * 2 + 1) * 16384);
#pragma unroll
        for (int i = 0; i < 8; ++i) {
            int ksp = kh * 8 + i;
            Bx0[i] = px[ksp * 64 + lane];
            Bx1[i] = px[1024 + ksp * 64 + lane];
            Bh0[i] = ph[ksp * 64 + lane];
            Bh1[i] = ph[1024 + ksp * 64 + lane];
        }
    }

    const int arow = m * 16 + (lane & 15);
    const int acol = (lane >> 4) * 8;
    const int r0 = m * 16 + (lane >> 4) * 4, c0 = lane & 15;
    float cx = 0.f;

    auto xgemm_store = [&](const bf16x8* af, int par) {
        f32x4 a0 = {0.f, 0.f, 0.f, 0.f}, a1 = {0.f, 0.f, 0.f, 0.f};
#pragma unroll
        for (int ks = 0; ks < 8; ++ks) {
            a0 = __builtin_amdgcn_mfma_f32_16x16x32_bf16(af[ks], Bx0[ks], a0, 0, 0, 0);
            a1 = __builtin_amdgcn_mfma_f32_16x16x32_bf16(af[ks], Bx1[ks], a1, 0, 0, 0);
        }
        float* zb = &zXs[par][kh][0];
#pragma unroll
        for (int r = 0; r < 4; ++r) {
            zb[(r0 + r) * 33 + c0]      = a0[r];
            zb[(r0 + r) * 33 + 16 + c0] = a1[r];
        }
    };

    // zX for t=0 (recurrence-independent)
    {
        const bf16x8* Ap = (const bf16x8*)(xb + (size_t)arow * 512 + kh * 256 + acol);
        bf16x8 af[8];
#pragma unroll
        for (int ks = 0; ks < 8; ++ks) af[ks] = Ap[ks * 4];
        xgemm_store(af, 0);
    }

    for (int t = 0; t < T_STEPS; ++t) {
        const int p = t & 1;

        // ---- recurrence-independent loads: issued BEFORE the tagged wait
        //      (the retry loop's implicit vmcnt(0) absorbs their latency) ----
        float xres = x[(size_t)t * 32768 + b * 512 + jg];
        float sxv = sx[t * 64 + b];
        float sqv = sq[t * 64 + b];
        bf16x8 afrN[8];                     // x A-frags for t+1
        if (t + 1 < T_STEPS) {
            const bf16x8* Ap = (const bf16x8*)(xb + (size_t)(t + 1) * 32768
                                               + arow * 512 + kh * 256 + acol);
#pragma unroll
            for (int ks = 0; ks < 8; ++ks) afrN[ks] = Ap[ks * 4];
        }

        // ---- tagged h load-and-wait: the load IS the sync ----
        ull hw[32];
        {
            const ull* hp = (const ull*)hxt + (size_t)p * 16384;
            const int g0 = kh * 32 + (lane >> 4);
            const int rb = arow * 4;
            const ull tag2 = ((ull)(unsigned)t << 32) | (unsigned)t;
            int slp = 0;
            for (;;) {
#pragma unroll
                for (int ks = 0; ks < 8; ++ks) {
                    const int idx = (g0 + ks * 4) * 256 + rb;
#pragma unroll
                    for (int j = 0; j < 4; ++j)
                        hw[ks * 4 + j] = __hip_atomic_load(hp + idx + j,
                            __ATOMIC_RELAXED, __HIP_MEMORY_SCOPE_AGENT);
                }
                ull bad = 0;
#pragma unroll
                for (int i = 0; i < 32; ++i)
                    bad |= (hw[i] & 0x0000FFFF0000FFFFull) ^ tag2;
                if (__all(bad == 0ull)) break;
                if      (slp == 0) __builtin_amdgcn_s_sleep(1);
                else if (slp == 1) __builtin_amdgcn_s_sleep(2);
                else               __builtin_amdgcn_s_sleep(4);
                if (slp < 2) ++slp;
            }
            asm volatile("" ::: "memory");
        }

        // ---- h-GEMM + exact LN stats from the tagged words ----
        {
            f32x4 h0 = {0.f, 0.f, 0.f, 0.f}, h1 = {0.f, 0.f, 0.f, 0.f};
            float s = 0.f, q = 0.f;
#pragma unroll
            for (int ks = 0; ks < 8; ++ks) {
                unsigned v[8];
#pragma unroll
                for (int j = 0; j < 4; ++j) {
                    v[2 * j]     = (unsigned)hw[ks * 4 + j];
                    v[2 * j + 1] = (unsigned)(hw[ks * 4 + j] >> 32);
                }
#pragma unroll
                for (int e = 0; e < 8; ++e) {
                    float f = __uint_as_float(v[e] & 0xffff0000u);  // exact bf16
                    s += f;
                    q = fmaf(f, f, q);
                }
                union { unsigned u[4]; bf16x8 bv; } fr;
#pragma unroll
                for (int j = 0; j < 4; ++j)
                    fr.u[j] = (v[2 * j] >> 16) | (v[2 * j + 1] & 0xffff0000u);
                h0 = __builtin_amdgcn_mfma_f32_16x16x32_bf16(fr.bv, Bh0[ks], h0, 0, 0, 0);
                h1 = __builtin_amdgcn_mfma_f32_16x16x32_bf16(fr.bv, Bh1[ks], h1, 0, 0, 0);
            }
            float* zb = &zHs[p][kh][0];
#pragma unroll
            for (int r = 0; r < 4; ++r) {
                zb[(r0 + r) * 33 + c0]      = h0[r];
                zb[(r0 + r) * 33 + 16 + c0] = h1[r];
            }
            // lanes {l, l^16, l^32, l^48} share arow
            s += __shfl_xor(s, 16); q += __shfl_xor(q, 16);
            s += __shfl_xor(s, 32); q += __shfl_xor(q, 32);
            if (lane < 16) {
                rsS[p][m * 16 + lane][kh] = s;
                rsQ[p][m * 16 + lane][kh] = q;
            }
        }
        __syncthreads();   // (A) the ONLY per-step barrier

        // ---- gates / state update (thread owns (b, jg)) ----
        float hval;
        {
            float hs = rsS[p][b][0] + rsS[p][b][1];
            float hq = rsQ[p][b][0] + rsQ[p][b][1];
            float mu = (sxv + hs) * (1.f / 1024.f);
            float var = (sqv + hq) * (1.f / 1024.f) - mu * mu;
            float rs = rsqrtf(var + 1e-5f);

            const float* zx0 = &zXs[p][0][0];
            const float* zx1 = &zXs[p][1][0];
            const float* zh0 = &zHs[p][0][0];
            const float* zh1 = &zHs[p][1][0];
            const int i0 = b * 33;
            float zf = zx0[i0 + jl]      + zx1[i0 + jl]      + zh0[i0 + jl]      + zh1[i0 + jl];
            float zi = zx0[i0 + 8 + jl]  + zx1[i0 + 8 + jl]  + zh0[i0 + 8 + jl]  + zh1[i0 + 8 + jl];
            float zg = zx0[i0 + 16 + jl] + zx1[i0 + 16 + jl] + zh0[i0 + 16 + jl] + zh1[i0 + 16 + jl];
            float zo = zx0[i0 + 24 + jl] + zx1[i0 + 24 + jl] + zh0[i0 + 24 + jl] + zh1[i0 + 24 + jl];
            zf = rs * (zf - mu * Scol[jl])      + Ccol[jl];
            zi = rs * (zi - mu * Scol[8 + jl])  + Ccol[8 + jl];
            zg = rs * (zg - mu * Scol[16 + jl]) + Ccol[16 + jl];
            zo = rs * (zo - mu * Scol[24 + jl]) + Ccol[24 + jl];

            float f  = 1.f / (1.f + __expf(-zf));
            float i_ = 1.f / (1.f + __expf(-zi));
            float gg = 2.f / (1.f + __expf(-2.f * zg)) - 1.f;
            float o_ = 1.f / (1.f + __expf(-zo));
            cx = f * cx + i_ * gg;
            float th = 2.f / (1.f + __expf(-2.f * cx)) - 1.f;
            hval = o_ * th + xres;
        }

        // ---- publish: ONE tagged 4B store per thread. No drain, no flag. ----
        if (t + 1 < T_STEPS) {
            unsigned tagged = ((unsigned)f2bf_bits(hval) << 16)
                            | (unsigned)(t + 1);
            __hip_atomic_store(hxt + (size_t)(p ^ 1) * 32768 + g * 512 + b * 8 + jl,
                               tagged, __ATOMIC_RELAXED, __HIP_MEMORY_SCOPE_AGENT);
        }

        // ---- shadow: out writes ----
        out[(size_t)t * 32768 + b * 512 + jg] = hval;
        if (t == T_STEPS - 1) {
            out[(size_t)T_STEPS * 32768 + b * 512 + jg] = hval;
            out[(size_t)T_STEPS * 32768 + 32768 + b * 512 + jg] = cx;
        }

        // ---- x-GEMM for t+1 from prefetched regs (off critical path) ----
        if (t + 1 < T_STEPS) xgemm_store(afrN, p ^ 1);
    }
}

// ---------------------------------------------------------------------------
extern "C" void kernel_launch(void* const* d_in, const int* in_sizes, int n_in,
                              void* d_out, int out_size, void* d_ws, size_t ws_size,
                              hipStream_t stream)
{
    const float* x    = (const float*)d_in[0];
    const float* ln_g = (const float*)d_in[1];
    const float* ln_b = (const float*)d_in[2];
    const float* Wf   = (const float*)d_in[3];
    const float* bf_  = (const float*)d_in[4];
    const float* Wi   = (const float*)d_in[5];
    const float* bi_  = (const float*)d_in[6];
    const float* Wg   = (const float*)d_in[7];
    const float* bg_  = (const float*)d_in[8];
    const float* Wo   = (const float*)d_in[9];
    const float* bo_  = (const float*)d_in[10];

    char* ws = (char*)d_ws;
    size_t off = 0;
    auto take = [&](size_t bytes) -> char* {
        char* p = ws + off;
        off += (bytes + 255) & ~(size_t)255;
        return p;
    };
    __hip_bfloat16* pack = (__hip_bfloat16*)take((size_t)2097152 * 2); // 4 MB
    float* S             = (float*)take(2048 * 4);
    float* C             = (float*)take(2048 * 4);
    __hip_bfloat16* xb   = (__hip_bfloat16*)take((size_t)33554432 * 2); // 64 MB
    float* sx            = (float*)take(65536 * 4);
    float* sq            = (float*)take(65536 * 4);
    char* ctrl = ws + off;
    unsigned int* hxt    = (unsigned int*)take((size_t)2 * 64 * 512 * 4); // 256 KB
    size_t ctrl_bytes = (size_t)((ws + off) - ctrl);

    hipMemsetAsync(ctrl, 0, ctrl_bytes, stream);
    pack_weights<<<dim3(128), dim3(256), 0, stream>>>(Wf, Wi, Wg, Wo, ln_g, pack);
    compute_sc<<<dim3(8), dim3(256), 0, stream>>>(Wf, Wi, Wg, Wo, bf_, bi_, bg_, bo_,
                                                  ln_g, ln_b, S, C);
    prep_x<<<dim3(16384), dim3(256), 0, stream>>>(x, xb, sx, sq);
    qlstm_main<<<dim3(NWG), dim3(512), 0, stream>>>(x, pack, S, C, xb, sx, sq,
                                                    hxt, (float*)d_out);
}